// Round 10
// baseline (97.596 us; speedup 1.0000x reference)
//
#include <hip/hip_runtime.h>
#include <stdint.h>

// Problem constants
//   N=16 samples, C=256 content channels, S=512 style channels, HW=64x64
//
// Algebraic reduction of the reference:
//   k[n][3][3]  = conv(style[n], dw_w) + dw_b               (9 scalars / sample)
//   s_d[n][c]   = mean over 4x4 of style[n][c]
//   pw1[n]      = s_d[n] . pw_kn_w + pw_kn_b                (1 scalar / sample)
//   bias[n][o]  = s_d[n] . pw_bias_w[o] + pw_bias_b[o]
//   Xs[n][h][w] = sum_c content[n][c][h][w]                 (channel sum)
//   D[n][h][w]  = 3x3 reflect-pad conv of Xs with k[n]
//   out[n][o][h][w] = 256*pw1[n]*D[n][h][w] + bias[n][o]
//
// SINGLE dispatch, per-sample producer->consumer flags (not a grid barrier):
//   bid   0..15  : style stats (k, scale, sd)      -> flag[n*33+32]
//   bid  16..527 : channel-sum slice -> final Xs   -> flag[n*33+sl]
//   bid 528..1551: consumers: prefetch bias rows, spin on their sample's 33
//                  flags, bias dot, Xs->LDS, reg conv, 4 plane stores.
// Producers occupy the lowest block IDs so the CP schedules them first.
// Flags are memset to 0 every call (async memset node) so replays are honest.
// Release: __threadfence + agent-scope atomic store. Acquire: agent-scope
// atomic load (invalidates XCD L2 -> no stale Xs across XCDs).

// workspace layout (float words)
#define OFF_SCALE 0                         // 16        : 256*pw1[n]
#define OFF_K     16                        // 16*9      : k[n][9]
#define OFF_SD    160                       // 16*512    : s_d[n][c]
#define OFF_XS    8352                      // 16*4096   : final channel-sum Xs
#define OFF_FLAG  73888                     // 16*33 uint32 flags
#define FLAG_MAGIC 0x5F3C9A17u

__global__ __launch_bounds__(256, 4) void ada_fused(
    const float* __restrict__ style,      // (16,512,4,4)
    const float* __restrict__ content,    // (16,256,64,64)
    const float* __restrict__ dw_w,       // (1,512,2,2)
    const float* __restrict__ dw_b,       // (1,)
    const float* __restrict__ pw_kn_w,    // (1,512,1,1)
    const float* __restrict__ pw_kn_b,    // (1,)
    const float* __restrict__ pw_bias_w,  // (256,512,1,1)
    const float* __restrict__ pw_bias_b,  // (256,)
    float* __restrict__ ws,
    float4* __restrict__ out)
{
    const int bid = blockIdx.x;           // 1552
    const int t   = threadIdx.x;          // 256
    uint32_t* flags = (uint32_t*)ws + OFF_FLAG;

    __shared__ float  red[4][10];
    __shared__ float4 part[8][32];
    __shared__ float  Xs[4096];
    __shared__ float  bias_s[4];

    if (bid < 16) {
        // ================== producer: per-sample style stats ==================
        const int n = bid;

        float acc[10];
#pragma unroll
        for (int j = 0; j < 10; ++j) acc[j] = 0.f;

#pragma unroll
        for (int cc = 0; cc < 2; ++cc) {
            const int c = t + cc * 256;
            const float4* sp = (const float4*)(style + ((size_t)n * 512 + c) * 16);
            float v[16];
#pragma unroll
            for (int q = 0; q < 4; ++q) {
                float4 f = sp[q];
                v[q*4+0] = f.x; v[q*4+1] = f.y; v[q*4+2] = f.z; v[q*4+3] = f.w;
            }
            float sum = 0.f;
#pragma unroll
            for (int q = 0; q < 16; ++q) sum += v[q];
            const float sdc = sum * 0.0625f;   // mean over 4x4
            ws[OFF_SD + n * 512 + c] = sdc;    // coalesced across t

            const float* w = dw_w + c * 4;     // [a*2+b]
            const float w00 = w[0], w01 = w[1], w10 = w[2], w11 = w[3];
#pragma unroll
            for (int ki = 0; ki < 3; ++ki)
#pragma unroll
                for (int kj = 0; kj < 3; ++kj)
                    acc[ki*3+kj] += v[ki*4 + kj]       * w00
                                  + v[ki*4 + kj + 1]   * w01
                                  + v[(ki+1)*4 + kj]   * w10
                                  + v[(ki+1)*4 + kj+1] * w11;
            acc[9] += sdc * pw_kn_w[c];
        }

#pragma unroll
        for (int off = 32; off >= 1; off >>= 1)
#pragma unroll
            for (int j = 0; j < 10; ++j)
                acc[j] += __shfl_down(acc[j], off, 64);

        if ((t & 63) == 0) {
#pragma unroll
            for (int j = 0; j < 10; ++j) red[t >> 6][j] = acc[j];
        }
        __syncthreads();

        if (t < 10) {
            const float s = red[0][t] + red[1][t] + red[2][t] + red[3][t];
            if (t < 9) ws[OFF_K + n * 9 + t] = s + dw_b[0];
            else       ws[OFF_SCALE + n]     = 256.f * (s + pw_kn_b[0]);
        }
        __syncthreads();                   // drain all global stores (vmcnt 0)
        if (t == 0) {
            __threadfence();
            __hip_atomic_store(&flags[n * 33 + 32], FLAG_MAGIC,
                               __ATOMIC_RELEASE, __HIP_MEMORY_SCOPE_AGENT);
        }
        return;
    }

    if (bid < 528) {
        // ============ producer: full channel-sum slice -> final Xs ============
        const int b   = bid - 16;         // 512 blocks
        const int n   = b >> 5;           // 16 samples
        const int sl  = b & 31;           // 32 slices of 32 float4
        const int col = t & 31;
        const int g   = t >> 5;           // 8 groups of 32 channels

        const float4* src = (const float4*)content
                          + ((size_t)(n * 256 + g * 32)) * 1024 + sl * 32 + col;
        float4 a = make_float4(0.f, 0.f, 0.f, 0.f);
#pragma unroll 8
        for (int c = 0; c < 32; ++c) {
            float4 v = src[(size_t)c * 1024];
            a.x += v.x; a.y += v.y; a.z += v.z; a.w += v.w;
        }
        part[g][col] = a;
        __syncthreads();
        if (g < 4) {
            float4 v = part[g + 4][col], u = part[g][col];
            part[g][col] = make_float4(u.x + v.x, u.y + v.y, u.z + v.z, u.w + v.w);
        }
        __syncthreads();
        if (g < 2) {
            float4 v = part[g + 2][col], u = part[g][col];
            part[g][col] = make_float4(u.x + v.x, u.y + v.y, u.z + v.z, u.w + v.w);
        }
        __syncthreads();
        if (g == 0) {
            float4 v = part[1][col], u = part[0][col];
            ((float4*)(ws + OFF_XS))[(size_t)n * 1024 + sl * 32 + col] =
                make_float4(u.x + v.x, u.y + v.y, u.z + v.z, u.w + v.w);
        }
        __syncthreads();                   // drain the g==0 global stores
        if (t == 0) {
            __threadfence();
            __hip_atomic_store(&flags[n * 33 + sl], FLAG_MAGIC,
                               __ATOMIC_RELEASE, __HIP_MEMORY_SCOPE_AGENT);
        }
        return;
    }

    // ======================= consumer: 4 output planes =======================
    const int c  = bid - 528;             // 1024
    const int n  = c >> 6;                // 16 samples
    const int s  = c & 63;                // plane group: planes s*4 .. s*4+3
    const int wv = t >> 6, l = t & 63;

    // prefetch this wave's bias row (independent of producers; hides in spin)
    const int o = s * 4 + wv;
    const float4* wr = (const float4*)(pw_bias_w + (size_t)o * 512);
    const float4 a0 = wr[l * 2], a1 = wr[l * 2 + 1];
    const float  bb = pw_bias_b[o];

    // spin until this sample's 33 producer blocks have released
    if (t < 33) {
        while (__hip_atomic_load(&flags[n * 33 + t],
                                 __ATOMIC_ACQUIRE, __HIP_MEMORY_SCOPE_AGENT)
               != FLAG_MAGIC)
            __builtin_amdgcn_s_sleep(8);
    }
    __syncthreads();

    // bias dot: wave wv -> row o
    {
        const float4* sv = (const float4*)(ws + OFF_SD + (size_t)n * 512);
        const float4 s0 = sv[l * 2], s1 = sv[l * 2 + 1];
        float d = a0.x*s0.x + a0.y*s0.y + a0.z*s0.z + a0.w*s0.w
                + a1.x*s1.x + a1.y*s1.y + a1.z*s1.z + a1.w*s1.w;
#pragma unroll
        for (int off = 32; off >= 1; off >>= 1)
            d += __shfl_down(d, off, 64);
        if (l == 0) bias_s[wv] = d + bb;
    }

    // Xs: final channel-sum, one coalesced 16 KB read
    const float4* xg = (const float4*)(ws + OFF_XS) + (size_t)n * 1024;
#pragma unroll
    for (int i = 0; i < 4; ++i)
        ((float4*)Xs)[i * 256 + t] = xg[i * 256 + t];

    float k[9];
#pragma unroll
    for (int j = 0; j < 9; ++j) k[j] = ws[OFF_K + n * 9 + j];
    const float scale = ws[OFF_SCALE + n];
    __syncthreads();                       // Xs + bias_s ready

    const float b0 = bias_s[0], b1 = bias_s[1], b2 = bias_s[2], b3 = bias_s[3];
    float4* obase = out + ((size_t)(n * 256 + s * 4)) * 1024;

    // conv in registers + interleaved stores.
#pragma unroll
    for (int q = 0; q < 4; ++q) {
        const int h  = q * 16 + (t >> 4);
        const int w0 = (t & 15) * 4;
        const int hm = (h == 0)  ? 1  : h - 1;   // reflect (no edge repeat)
        const int hp = (h == 63) ? 62 : h + 1;
        float e0 = 0.f, e1 = 0.f, e2 = 0.f, e3 = 0.f;
        const int rows[3] = { hm, h, hp };
#pragma unroll
        for (int i = 0; i < 3; ++i) {
            const float* R = &Xs[rows[i] * 64];
            const float4 m    = *(const float4*)&R[w0];        // cols w0..w0+3
            const float  left  = (w0 == 0)  ? R[1]  : R[w0 - 1];
            const float  right = (w0 == 60) ? R[62] : R[w0 + 4];
            const float k0 = k[i*3], k1 = k[i*3+1], k2 = k[i*3+2];
            e0 += k0*left + k1*m.x + k2*m.y;
            e1 += k0*m.x  + k1*m.y + k2*m.z;
            e2 += k0*m.y  + k1*m.z + k2*m.w;
            e3 += k0*m.z  + k1*m.w + k2*right;
        }
        e0 *= scale; e1 *= scale; e2 *= scale; e3 *= scale;

        float4* ob = obase + q * 256 + t;
        ob[0]    = make_float4(e0 + b0, e1 + b0, e2 + b0, e3 + b0);
        ob[1024] = make_float4(e0 + b1, e1 + b1, e2 + b1, e3 + b1);
        ob[2048] = make_float4(e0 + b2, e1 + b2, e2 + b2, e3 + b2);
        ob[3072] = make_float4(e0 + b3, e1 + b3, e2 + b3, e3 + b3);
    }
}

// ---------------------------------------------------------------- launch
extern "C" void kernel_launch(void* const* d_in, const int* in_sizes, int n_in,
                              void* d_out, int out_size, void* d_ws, size_t ws_size,
                              hipStream_t stream)
{
    const float* style     = (const float*)d_in[0];
    const float* content   = (const float*)d_in[1];
    const float* dw_w      = (const float*)d_in[2];
    const float* dw_b      = (const float*)d_in[3];
    const float* pw_kn_w   = (const float*)d_in[4];
    const float* pw_kn_b   = (const float*)d_in[5];
    const float* pw_bias_w = (const float*)d_in[6];
    const float* pw_bias_b = (const float*)d_in[7];
    float*  ws  = (float*)d_ws;
    float4* out = (float4*)d_out;

    // zero the 16*33 readiness flags every call (graph-legal memset node)
    hipMemsetAsync((char*)d_ws + (size_t)OFF_FLAG * 4, 0, 16 * 33 * 4, stream);

    ada_fused<<<1552, 256, 0, stream>>>(style, content, dw_w, dw_b,
                                        pw_kn_w, pw_kn_b,
                                        pw_bias_w, pw_bias_b, ws, out);
}

// Round 11
// 28.925 us; speedup vs baseline: 3.3742x; 3.3742x over previous
//
#include <hip/hip_runtime.h>

// Problem constants
//   N=16 samples, C=256 content channels, S=512 style channels, HW=64x64
//
// Algebraic reduction of the reference:
//   k[n][3][3]  = conv(style[n], dw_w) + dw_b               (9 scalars / sample)
//   s_d[n][c]   = mean over 4x4 of style[n][c]
//   pw1[n]      = s_d[n] . pw_kn_w + pw_kn_b                (1 scalar / sample)
//   bias[n][o]  = s_d[n] . pw_bias_w[o] + pw_bias_b[o]
//   Xs[n][h][w] = sum_c content[n][c][h][w]                 (channel sum)
//   D[n][h][w]  = 3x3 reflect-pad conv of Xs with k[n]
//   out[n][o][h][w] = 256*pw1[n]*D[n][h][w] + bias[n][o]
//
// Round-10 lesson: single-kernel producer/consumer fusion starves itself
// (spinning consumers hold residency slots). 2-dispatch structure is final.
// This round's single change: chsum 512 -> 1024 blocks (4/CU co-resident,
// 2x outstanding reads) to attack read-side latency on L3 hits.
//
// K1: style stats (blocks 0-15) + full channel-sum (blocks 16..1039: block =
//     (n, 16-float4 slice); thread (g=t>>4, col=t&15) sums 16 channels; 4-step
//     LDS tree; writes FINAL Xs (256 KB total)).
// K2: 1024 blocks x 4 planes: bias dot -> Xs 16 KB L2 read -> sync -> conv in
//     registers + interleaved 4-plane stores.

// workspace layout (floats)
#define OFF_SCALE 0                         // 16        : 256*pw1[n]
#define OFF_K     16                        // 16*9      : k[n][9]
#define OFF_SD    160                       // 16*512    : s_d[n][c]
#define OFF_XS    8352                      // 16*4096   : final channel-sum Xs

// ---------------------------------------------------------------- kernel 1
__global__ __launch_bounds__(256, 4) void ada_front(
    const float* __restrict__ style,      // (16,512,4,4)
    const float* __restrict__ content,    // (16,256,64,64)
    const float* __restrict__ dw_w,       // (1,512,2,2)
    const float* __restrict__ dw_b,       // (1,)
    const float* __restrict__ pw_kn_w,    // (1,512,1,1)
    const float* __restrict__ pw_kn_b,    // (1,)
    float* __restrict__ ws)
{
    const int t = threadIdx.x;
    __shared__ float red[4][10];
    __shared__ float4 part[16][16];

    if (blockIdx.x >= 16) {
        // ---- full channel-sum: block (n, sl) sums all 256 channels of a
        // 16-float4 slice. thread: col = t&15, ch-group g = t>>4 (16 ch each).
        const int b   = blockIdx.x - 16;  // 1024 blocks
        const int n   = b >> 6;           // 16 samples
        const int sl  = b & 63;           // 64 slices of 16 float4
        const int col = t & 15;
        const int g   = t >> 4;

        const float4* src = (const float4*)content
                          + ((size_t)(n * 256 + g * 16)) * 1024 + sl * 16 + col;
        float4 a = make_float4(0.f, 0.f, 0.f, 0.f);
#pragma unroll 16
        for (int c = 0; c < 16; ++c) {
            float4 v = src[(size_t)c * 1024];
            a.x += v.x; a.y += v.y; a.z += v.z; a.w += v.w;
        }
        part[g][col] = a;
        __syncthreads();
        if (g < 8) {
            float4 v = part[g + 8][col], u = part[g][col];
            part[g][col] = make_float4(u.x + v.x, u.y + v.y, u.z + v.z, u.w + v.w);
        }
        __syncthreads();
        if (g < 4) {
            float4 v = part[g + 4][col], u = part[g][col];
            part[g][col] = make_float4(u.x + v.x, u.y + v.y, u.z + v.z, u.w + v.w);
        }
        __syncthreads();
        if (g < 2) {
            float4 v = part[g + 2][col], u = part[g][col];
            part[g][col] = make_float4(u.x + v.x, u.y + v.y, u.z + v.z, u.w + v.w);
        }
        __syncthreads();
        if (g == 0) {
            float4 v = part[1][col], u = part[0][col];
            ((float4*)(ws + OFF_XS))[(size_t)n * 1024 + sl * 16 + col] =
                make_float4(u.x + v.x, u.y + v.y, u.z + v.z, u.w + v.w);
        }
        return;
    }

    // ---- per-sample style stats (slim: k, scale, sd only)
    const int n = blockIdx.x;

    float acc[10];
#pragma unroll
    for (int j = 0; j < 10; ++j) acc[j] = 0.f;

#pragma unroll
    for (int cc = 0; cc < 2; ++cc) {
        const int c = t + cc * 256;
        const float4* sp = (const float4*)(style + ((size_t)n * 512 + c) * 16);
        float v[16];
#pragma unroll
        for (int q = 0; q < 4; ++q) {
            float4 f = sp[q];
            v[q*4+0] = f.x; v[q*4+1] = f.y; v[q*4+2] = f.z; v[q*4+3] = f.w;
        }
        float sum = 0.f;
#pragma unroll
        for (int q = 0; q < 16; ++q) sum += v[q];
        const float sdc = sum * 0.0625f;   // mean over 4x4
        ws[OFF_SD + n * 512 + c] = sdc;    // coalesced across t

        const float* w = dw_w + c * 4;     // [a*2+b]
        const float w00 = w[0], w01 = w[1], w10 = w[2], w11 = w[3];
#pragma unroll
        for (int ki = 0; ki < 3; ++ki)
#pragma unroll
            for (int kj = 0; kj < 3; ++kj)
                acc[ki*3+kj] += v[ki*4 + kj]       * w00
                              + v[ki*4 + kj + 1]   * w01
                              + v[(ki+1)*4 + kj]   * w10
                              + v[(ki+1)*4 + kj+1] * w11;
        acc[9] += sdc * pw_kn_w[c];
    }

    // wave(64)-level butterfly reduce of the 10 partials
#pragma unroll
    for (int off = 32; off >= 1; off >>= 1)
#pragma unroll
        for (int j = 0; j < 10; ++j)
            acc[j] += __shfl_down(acc[j], off, 64);

    if ((t & 63) == 0) {
#pragma unroll
        for (int j = 0; j < 10; ++j) red[t >> 6][j] = acc[j];
    }
    __syncthreads();

    if (t < 10) {
        const float s = red[0][t] + red[1][t] + red[2][t] + red[3][t];
        if (t < 9) ws[OFF_K + n * 9 + t] = s + dw_b[0];
        else       ws[OFF_SCALE + n]     = 256.f * (s + pw_kn_b[0]);
    }
}

// ---------------------------------------------------------------- kernel 2
// 1024 blocks: block (n, s) -> planes s*4 .. s*4+3 of sample n.
//   1. bias dot (wave wv -> row s*4+wv)
//   2. Xs load: one 16 KB coalesced L2 read into LDS
//   3. single sync; conv in registers per 4-point quad, stores interleaved
__global__ __launch_bounds__(256, 2) void ada_back(
    const float* __restrict__ ws,
    const float* __restrict__ pw_bias_w,  // (256,512)
    const float* __restrict__ pw_bias_b,  // (256,)
    float4* __restrict__ out)
{
    const int bid = blockIdx.x;     // 1024
    const int n   = bid >> 6;       // 16 samples
    const int s   = bid & 63;       // plane group
    const int t   = threadIdx.x;

    __shared__ float Xs[4096];      // channel-sum image, row-major 64x64
    __shared__ float bias_s[4];

    // ---- 1. per-block bias: wave wv computes row o = s*4 + wv
    {
        const int wv = t >> 6, l = t & 63;
        const int o  = s * 4 + wv;
        const float4* wr = (const float4*)(pw_bias_w + (size_t)o * 512);
        const float4* sv = (const float4*)(ws + OFF_SD + (size_t)n * 512);
        const float4 a0 = wr[l * 2],     a1 = wr[l * 2 + 1];
        const float4 s0 = sv[l * 2],     s1 = sv[l * 2 + 1];
        float d = a0.x*s0.x + a0.y*s0.y + a0.z*s0.z + a0.w*s0.w
                + a1.x*s1.x + a1.y*s1.y + a1.z*s1.z + a1.w*s1.w;
#pragma unroll
        for (int off = 32; off >= 1; off >>= 1)
            d += __shfl_down(d, off, 64);
        if (l == 0) bias_s[wv] = d + pw_bias_b[o];
    }

    // ---- 2. Xs: final channel-sum, one coalesced 16 KB read
    const float4* xg = (const float4*)(ws + OFF_XS) + (size_t)n * 1024;
#pragma unroll
    for (int i = 0; i < 4; ++i)
        ((float4*)Xs)[i * 256 + t] = xg[i * 256 + t];

    float k[9];
#pragma unroll
    for (int j = 0; j < 9; ++j) k[j] = ws[OFF_K + n * 9 + j];
    const float scale = ws[OFF_SCALE + n];
    __syncthreads();                // Xs + bias_s ready

    const float b0 = bias_s[0], b1 = bias_s[1], b2 = bias_s[2], b3 = bias_s[3];
    float4* obase = out + ((size_t)(n * 256 + s * 4)) * 1024;

    // ---- 3. conv in registers + interleaved stores.
    // thread t, quad q -> points (h, w0..w0+3), h = q*16 + t/16, w0 = (t%16)*4
#pragma unroll
    for (int q = 0; q < 4; ++q) {
        const int h  = q * 16 + (t >> 4);
        const int w0 = (t & 15) * 4;
        const int hm = (h == 0)  ? 1  : h - 1;   // reflect (no edge repeat)
        const int hp = (h == 63) ? 62 : h + 1;
        float e0 = 0.f, e1 = 0.f, e2 = 0.f, e3 = 0.f;
        const int rows[3] = { hm, h, hp };
#pragma unroll
        for (int i = 0; i < 3; ++i) {
            const float* R = &Xs[rows[i] * 64];
            const float4 m    = *(const float4*)&R[w0];        // cols w0..w0+3
            const float  left  = (w0 == 0)  ? R[1]  : R[w0 - 1];
            const float  right = (w0 == 60) ? R[62] : R[w0 + 4];
            const float k0 = k[i*3], k1 = k[i*3+1], k2 = k[i*3+2];
            e0 += k0*left + k1*m.x + k2*m.y;
            e1 += k0*m.x  + k1*m.y + k2*m.z;
            e2 += k0*m.y  + k1*m.z + k2*m.w;
            e3 += k0*m.z  + k1*m.w + k2*right;
        }
        e0 *= scale; e1 *= scale; e2 *= scale; e3 *= scale;

        float4* o = obase + q * 256 + t;
        o[0]    = make_float4(e0 + b0, e1 + b0, e2 + b0, e3 + b0);
        o[1024] = make_float4(e0 + b1, e1 + b1, e2 + b1, e3 + b1);
        o[2048] = make_float4(e0 + b2, e1 + b2, e2 + b2, e3 + b2);
        o[3072] = make_float4(e0 + b3, e1 + b3, e2 + b3, e3 + b3);
    }
}

// ---------------------------------------------------------------- launch
extern "C" void kernel_launch(void* const* d_in, const int* in_sizes, int n_in,
                              void* d_out, int out_size, void* d_ws, size_t ws_size,
                              hipStream_t stream)
{
    const float* style     = (const float*)d_in[0];
    const float* content   = (const float*)d_in[1];
    const float* dw_w      = (const float*)d_in[2];
    const float* dw_b      = (const float*)d_in[3];
    const float* pw_kn_w   = (const float*)d_in[4];
    const float* pw_kn_b   = (const float*)d_in[5];
    const float* pw_bias_w = (const float*)d_in[6];
    const float* pw_bias_b = (const float*)d_in[7];
    float*  ws  = (float*)d_ws;
    float4* out = (float4*)d_out;

    ada_front<<<16 + 1024, 256, 0, stream>>>(style, content, dw_w, dw_b,
                                             pw_kn_w, pw_kn_b, ws);
    ada_back <<<1024,      256, 0, stream>>>(ws, pw_bias_w, pw_bias_b, out);
}